// Round 3
// baseline (269.594 us; speedup 1.0000x reference)
//
#include <hip/hip_runtime.h>
#include <cstdint>

// ---------------------------------------------------------------------------
// minerva_transform: logits = (l2(Xe) @ l2(De)^T)^3 @ rh ; preds = sigmoid
// R6: k_minerva REVERTED to R3's 128^2 2-barrier version (known 112 us; the
// 256^2 4-phase pipeline lost at K=512 even with spills fixed - short-K
// regime, pipeline fill dominates).  New: k_prep's X/D bf16 round-trip
// eliminated - k_embed reg-stages A directly from fp32 (load float4 -> cvt ->
// ds_write_b128 into the SAME swizzled LDS layout); k_prep now only converts
// G + computes rh + zeros accumulators.  Saves ~75 MB of HBM traffic.
// ---------------------------------------------------------------------------

typedef __attribute__((ext_vector_type(4))) float  f32x4;
typedef __attribute__((ext_vector_type(8))) __bf16 bf16x8;
typedef __attribute__((ext_vector_type(4))) __bf16 bf16x4;

constexpr int B = 4096, N = 20000, F = 768, E = 512;

#define AS1CAST(p) ((__attribute__((address_space(1))) unsigned int*)(uintptr_t)(p))
#define AS3CAST(p) ((__attribute__((address_space(3))) unsigned int*)(uintptr_t)(p))

__device__ __forceinline__ void gload_lds16(const void* g, void* l) {
  // 16B/lane, LDS dest = wave-uniform base + lane*16 (layout guarantees this)
  __builtin_amdgcn_global_load_lds(AS1CAST(g), AS3CAST(l), 16, 0, 0);
}

// ------------------------- slim prep ---------------------------------------
// G fp32->bf16 (tiny), rh = (2r-1)*hw+hb, zero lg/norm2.  Grid covers all.

__global__ void k_prep(const float* __restrict__ G, const float* __restrict__ r,
                       const float* __restrict__ hw, const float* __restrict__ hb,
                       __bf16* __restrict__ Gb, float* __restrict__ rh,
                       float* __restrict__ lg, float* __restrict__ norm2) {
  const int t = blockIdx.x * blockDim.x + threadIdx.x;
  constexpr int nG = E * F / 4;   // 98304 float4 groups
  if (t < nG) {
    float4 v = ((const float4*)G)[t];
    bf16x4 o;
    o[0] = (__bf16)v.x; o[1] = (__bf16)v.y; o[2] = (__bf16)v.z; o[3] = (__bf16)v.w;
    ((bf16x4*)Gb)[t] = o;
  }
  if (t < N) rh[t] = (2.0f * r[t] - 1.0f) * hw[0] + hb[0];
  if (t < B) lg[t] = 0.0f;
  if (t < B + N) norm2[t] = 0.0f;
}

// ------------------------- combined embedding GEMM -------------------------
// row-tiles 0..31 = X, 32..188 = D.  Eb[g,e] = bf16(sum_k A[m,k]G[e,k]+b[e]),
// norm2[g] += sum_e Eb[g,e]^2.  BK=64, XOR-swizzled LDS (conflict-free).
// A-side: reg-staged fp32->bf16 (reads original X/D, no bf16 pre-pass);
// B-side (G): async global_load_lds from pre-converted Gb.

__global__ __launch_bounds__(256, 3)
void k_embed(const float* __restrict__ Xf, const float* __restrict__ Df,
             const __bf16* __restrict__ Gb, const float* __restrict__ bias,
             __bf16* __restrict__ Eb, float* __restrict__ norm2) {
  constexpr int K = F;  // 768
  __shared__ __bf16 As[128 * 64];
  __shared__ __bf16 Bs[128 * 64];
  __shared__ float ssum[128];
  const int tid  = threadIdx.x;
  const int wave = tid >> 6;
  const int lane = tid & 63;
  const int by = blockIdx.y;
  const bool isX = (by < B / 128);
  const float* A = isX ? Xf : Df;
  const int m0 = isX ? by * 128 : (by - B / 128) * 128;
  const int Mr = isX ? B : N;
  const int g0 = by * 128;              // row offset into Eb / norm2
  const int n0 = blockIdx.x * 128;      // e-dim tile
  if (tid < 128) ssum[tid] = 0.0f;

  // staging: thread t -> row=(t>>3)+q*32, global colgrp (t&7)^(row&7).
  // LDS dest element q*2048 + tid*8 == row*64 + (t&7)*8 (same layout as the
  // old gload_lds path, so the fragment reads below are unchanged).
  const int srow = tid >> 3;
  const int scg  = (tid & 7) ^ (srow & 7);
  const float*  ga[4];
  const __bf16* gb[4];
  __bf16* la[4];
  __bf16* lb[4];
#pragma unroll
  for (int q = 0; q < 4; ++q) {
    const int row = srow + q * 32;
    int arow = m0 + row; if (arow >= Mr) arow = Mr - 1;
    const int brow = n0 + row;                       // < 512 always
    ga[q] = A  + (size_t)arow * K + scg * 8;
    gb[q] = Gb + (size_t)brow * K + scg * 8;
    la[q] = &As[q * 2048 + tid * 8];
    lb[q] = &Bs[q * 2048 + tid * 8];
  }

  const int mw = (wave & 1) * 64;
  const int nw = (wave >> 1) * 64;
  const int quad = lane >> 4;
  const int l15  = lane & 15;
  f32x4 acc[4][4] = {};

  for (int kb = 0; kb < K; kb += 64) {
    // B: async direct-to-LDS (bf16)
#pragma unroll
    for (int q = 0; q < 4; ++q) gload_lds16(gb[q] + kb, lb[q]);
    // A: reg-stage fp32 -> bf16 (issue all loads first for overlap)
    float4 av[4][2];
#pragma unroll
    for (int q = 0; q < 4; ++q) {
      av[q][0] = *(const float4*)(ga[q] + kb);
      av[q][1] = *(const float4*)(ga[q] + kb + 4);
    }
#pragma unroll
    for (int q = 0; q < 4; ++q) {
      bf16x8 o;
      o[0] = (__bf16)av[q][0].x; o[1] = (__bf16)av[q][0].y;
      o[2] = (__bf16)av[q][0].z; o[3] = (__bf16)av[q][0].w;
      o[4] = (__bf16)av[q][1].x; o[5] = (__bf16)av[q][1].y;
      o[6] = (__bf16)av[q][1].z; o[7] = (__bf16)av[q][1].w;
      *(bf16x8*)la[q] = o;
    }
    __syncthreads();
#pragma unroll
    for (int h = 0; h < 2; ++h) {
      bf16x8 af[4], bfr[4];
#pragma unroll
      for (int i = 0; i < 4; ++i) {
        const int rr = mw + i * 16 + l15;
        af[i] = *(const bf16x8*)&As[rr * 64 + ((quad + h * 4) ^ (rr & 7)) * 8];
      }
#pragma unroll
      for (int j = 0; j < 4; ++j) {
        const int rr = nw + j * 16 + l15;
        bfr[j] = *(const bf16x8*)&Bs[rr * 64 + ((quad + h * 4) ^ (rr & 7)) * 8];
      }
#pragma unroll
      for (int i = 0; i < 4; ++i)
#pragma unroll
        for (int j = 0; j < 4; ++j)
          acc[i][j] = __builtin_amdgcn_mfma_f32_16x16x32_bf16(af[i], bfr[j], acc[i][j], 0, 0, 0);
    }
    __syncthreads();
  }

  // epilogue: bf16 store + row sum-of-squares.  C/D: col=l15, row=quad*4+reg
#pragma unroll
  for (int i = 0; i < 4; ++i) {
    float part[4] = {0.0f, 0.0f, 0.0f, 0.0f};
#pragma unroll
    for (int j = 0; j < 4; ++j) {
      const int col = n0 + nw + j * 16 + l15;
      const float bv = bias[col];
#pragma unroll
      for (int rr = 0; rr < 4; ++rr) {
        const int row = mw + i * 16 + quad * 4 + rr;   // tile-local
        if (m0 + row < Mr) {
          const __bf16 hv = (__bf16)(acc[i][j][rr] + bv);
          Eb[(size_t)(g0 + row) * E + col] = hv;
          const float vb = (float)hv;
          part[rr] += vb * vb;
        }
      }
    }
#pragma unroll
    for (int rr = 0; rr < 4; ++rr) {
      float v = part[rr];
      v += __shfl_xor(v, 1);
      v += __shfl_xor(v, 2);
      v += __shfl_xor(v, 4);
      v += __shfl_xor(v, 8);
      if (l15 == 0) atomicAdd(&ssum[mw + i * 16 + quad * 4 + rr], v);
    }
  }
  __syncthreads();
  if (tid < 128 && m0 + tid < Mr) atomicAdd(&norm2[g0 + tid], ssum[tid]);
}

// ------------------------- fused Minerva GEMM (R3 version) -----------------
// acc = Xe@De^T (unnormalized, K=512); epilogue uses
//   s^3*rh = acc^3 * ix^3 * (id^3*rh),  ix^3 hoisted out of the j-loop.
// m-fast panel ordering: consecutive blocks share the n-progression so each
// XCD's L2 holds a small Xn slice + the Dn panel.

__global__ __launch_bounds__(256, 3)
void k_minerva(const __bf16* __restrict__ Xe, const __bf16* __restrict__ De,
               const float* __restrict__ norm2, const float* __restrict__ rh,
               float* __restrict__ logits) {
  constexpr int K  = 512;
  constexpr int MT = B / 128;          // 32
  constexpr int NT = (N + 127) / 128;  // 157
  constexpr int W  = 20;               // panel width (n-tiles)
  __shared__ __bf16 As[128 * 64];
  __shared__ __bf16 Bs[128 * 64];
  __shared__ float lsum[128];
  const int tid  = threadIdx.x;
  const int lane = tid & 63;
  const int wave = tid >> 6;

  // panel decomposition, m-fast within panel
  const int bid   = blockIdx.x;
  const int panel = bid / (W * MT);
  const int bn    = panel * W;
  const int rem   = bid - panel * (W * MT);
  const int mt    = rem % MT;
  const int nt    = bn + rem / MT;
  const int m0 = mt * 128, n0 = nt * 128;
  if (tid < 128) lsum[tid] = 0.0f;

  const int srow = tid >> 3;
  const int scg  = (tid & 7) ^ (srow & 7);
  const __bf16* ga[4];
  const __bf16* gb[4];
  __bf16* la[4];
  __bf16* lb[4];
#pragma unroll
  for (int q = 0; q < 4; ++q) {
    const int row = srow + q * 32;
    const int arow = m0 + row;                       // < 4096 always
    int brow = n0 + row; if (brow >= N) brow = N - 1;
    ga[q] = Xe + (size_t)arow * K + scg * 8;
    gb[q] = De + (size_t)brow * K + scg * 8;
    la[q] = &As[q * 2048 + tid * 8];
    lb[q] = &Bs[q * 2048 + tid * 8];
  }

  const int mw = (wave & 1) * 64;
  const int nw = (wave >> 1) * 64;
  const int quad = lane >> 4;
  const int l15  = lane & 15;
  f32x4 acc[4][4] = {};

  for (int kb = 0; kb < K; kb += 64) {
#pragma unroll
    for (int q = 0; q < 4; ++q) gload_lds16(ga[q] + kb, la[q]);
#pragma unroll
    for (int q = 0; q < 4; ++q) gload_lds16(gb[q] + kb, lb[q]);
    __syncthreads();
#pragma unroll
    for (int h = 0; h < 2; ++h) {
      bf16x8 af[4], bfr[4];
#pragma unroll
      for (int i = 0; i < 4; ++i) {
        const int rr = mw + i * 16 + l15;
        af[i] = *(const bf16x8*)&As[rr * 64 + ((quad + h * 4) ^ (rr & 7)) * 8];
      }
#pragma unroll
      for (int j = 0; j < 4; ++j) {
        const int rr = nw + j * 16 + l15;
        bfr[j] = *(const bf16x8*)&Bs[rr * 64 + ((quad + h * 4) ^ (rr & 7)) * 8];
      }
#pragma unroll
      for (int i = 0; i < 4; ++i)
#pragma unroll
        for (int j = 0; j < 4; ++j)
          acc[i][j] = __builtin_amdgcn_mfma_f32_16x16x32_bf16(af[i], bfr[j], acc[i][j], 0, 0, 0);
    }
    __syncthreads();
  }

  // ---- epilogue ----
  float id3rh[4];
#pragma unroll
  for (int j = 0; j < 4; ++j) {
    const int col = n0 + nw + j * 16 + l15;
    if (col < N) {
      const float id = 1.0f / fmaxf(sqrtf(norm2[B + col]), 1e-12f);
      id3rh[j] = id * id * id * rh[col];
    } else id3rh[j] = 0.0f;   // kills padded/clamped cols
  }
#pragma unroll
  for (int i = 0; i < 4; ++i) {
    float ix3[4];
#pragma unroll
    for (int rr = 0; rr < 4; ++rr) {
      const int row = m0 + mw + i * 16 + quad * 4 + rr;   // < 4096
      const float ix = 1.0f / fmaxf(sqrtf(norm2[row]), 1e-12f);
      ix3[rr] = ix * ix * ix;
    }
    float part[4] = {0.0f, 0.0f, 0.0f, 0.0f};
#pragma unroll
    for (int j = 0; j < 4; ++j)
#pragma unroll
      for (int rr = 0; rr < 4; ++rr) {
        const float a = acc[i][j][rr];
        const float a2 = a * a;
        part[rr] = fmaf(a2 * a, id3rh[j], part[rr]);
      }
#pragma unroll
    for (int rr = 0; rr < 4; ++rr) {
      float v = part[rr] * ix3[rr];
      v += __shfl_xor(v, 1);
      v += __shfl_xor(v, 2);
      v += __shfl_xor(v, 4);
      v += __shfl_xor(v, 8);
      if (l15 == 0) atomicAdd(&lsum[mw + i * 16 + quad * 4 + rr], v);
    }
  }
  __syncthreads();
  if (tid < 128) atomicAdd(&logits[m0 + tid], lsum[tid]);
}

// ------------------------- finalize ----------------------------------------

__global__ void k_finalize(const float* __restrict__ logits, float* __restrict__ out, int n) {
  int i = blockIdx.x * blockDim.x + threadIdx.x;
  if (i < n) {
    float L = logits[i];
    out[i] = L;
    out[n + i] = 1.0f / (1.0f + expf(-L));
  }
}

// ------------------------- launcher ----------------------------------------

extern "C" void kernel_launch(void* const* d_in, const int* in_sizes, int n_in,
                              void* d_out, int out_size, void* d_ws, size_t ws_size,
                              hipStream_t stream) {
  const float* X   = (const float*)d_in[0];
  const float* D   = (const float*)d_in[1];
  const float* r   = (const float*)d_in[2];
  const float* g_w = (const float*)d_in[3];
  const float* g_b = (const float*)d_in[4];
  const float* h_w = (const float*)d_in[5];
  const float* h_b = (const float*)d_in[6];
  float* out = (float*)d_out;

  // ws layout (bytes), 256-aligned, total ~25.7 MB
  char* ws = (char*)d_ws;
  __bf16* Gb    = (__bf16*)(ws + 0);             // 512*768*2    = 786,432
  __bf16* Eb    = (__bf16*)(ws + 786432);        // 24096*512*2  = 24,674,304
  float*  rh    = (float*) (ws + 25460736);      // 20000*4      = 80,000
  float*  norm2 = (float*) (ws + 25540736);      // 24096*4      = 96,384
  float*  lg    = (float*) (ws + 25637120);      // 4096*4       = 16,384

  // 1. slim prep: G convert + rh + zero (384*256 = 98304 threads covers all)
  k_prep<<<384, 256, 0, stream>>>(g_w, r, h_w, h_b, Gb, rh, lg, norm2);

  // 2. combined embedding GEMM (A reg-staged from fp32), bf16 out + norm2
  k_embed<<<dim3(E / 128, B / 128 + (N + 127) / 128), 256, 0, stream>>>(
      X, D, Gb, g_b, Eb, norm2);

  // 3. fused cosine^3-weighted retrieval (normalization folded into epilogue)
  k_minerva<<<157 * 32, 256, 0, stream>>>(Eb, Eb + (size_t)B * E, norm2, rh, lg);

  // 4. logits + sigmoid
  k_finalize<<<(B + 255) / 256, 256, 0, stream>>>(lg, out, B);
}

// Round 4
// 267.736 us; speedup vs baseline: 1.0069x; 1.0069x over previous
//
#include <hip/hip_runtime.h>
#include <cstdint>

// ---------------------------------------------------------------------------
// minerva_transform: logits = (l2(Xe) @ l2(De)^T)^3 @ rh ; preds = sigmoid
// R7: single change vs R6 - k_minerva __launch_bounds__(256,3) -> (256,4).
// Occupancy 3->4 blocks/CU (LDS 33.3KB*4=133KB<160KB; unified VGPR
// 64 arch + 64 AGPR = 128/wave * 16 waves = the vgpr=128 occupancy step).
// k_minerva is latency/barrier-bound (MfmaUtil 29, VALUBusy 40, Occ 41%);
// extra resident block gives the CU more waves at other phases to hide the
// per-K-step vmcnt(0) barrier drain (m114 mechanism).
// k_prep / k_embed / k_finalize unchanged from R6.
// ---------------------------------------------------------------------------

typedef __attribute__((ext_vector_type(4))) float  f32x4;
typedef __attribute__((ext_vector_type(8))) __bf16 bf16x8;
typedef __attribute__((ext_vector_type(4))) __bf16 bf16x4;

constexpr int B = 4096, N = 20000, F = 768, E = 512;

#define AS1CAST(p) ((__attribute__((address_space(1))) unsigned int*)(uintptr_t)(p))
#define AS3CAST(p) ((__attribute__((address_space(3))) unsigned int*)(uintptr_t)(p))

__device__ __forceinline__ void gload_lds16(const void* g, void* l) {
  // 16B/lane, LDS dest = wave-uniform base + lane*16 (layout guarantees this)
  __builtin_amdgcn_global_load_lds(AS1CAST(g), AS3CAST(l), 16, 0, 0);
}

// ------------------------- slim prep ---------------------------------------
// G fp32->bf16 (tiny), rh = (2r-1)*hw+hb, zero lg/norm2.  Grid covers all.

__global__ void k_prep(const float* __restrict__ G, const float* __restrict__ r,
                       const float* __restrict__ hw, const float* __restrict__ hb,
                       __bf16* __restrict__ Gb, float* __restrict__ rh,
                       float* __restrict__ lg, float* __restrict__ norm2) {
  const int t = blockIdx.x * blockDim.x + threadIdx.x;
  constexpr int nG = E * F / 4;   // 98304 float4 groups
  if (t < nG) {
    float4 v = ((const float4*)G)[t];
    bf16x4 o;
    o[0] = (__bf16)v.x; o[1] = (__bf16)v.y; o[2] = (__bf16)v.z; o[3] = (__bf16)v.w;
    ((bf16x4*)Gb)[t] = o;
  }
  if (t < N) rh[t] = (2.0f * r[t] - 1.0f) * hw[0] + hb[0];
  if (t < B) lg[t] = 0.0f;
  if (t < B + N) norm2[t] = 0.0f;
}

// ------------------------- combined embedding GEMM -------------------------
// row-tiles 0..31 = X, 32..188 = D.  Eb[g,e] = bf16(sum_k A[m,k]G[e,k]+b[e]),
// norm2[g] += sum_e Eb[g,e]^2.  BK=64, XOR-swizzled LDS (conflict-free).
// A-side: reg-staged fp32->bf16 (reads original X/D, no bf16 pre-pass);
// B-side (G): async global_load_lds from pre-converted Gb.

__global__ __launch_bounds__(256, 3)
void k_embed(const float* __restrict__ Xf, const float* __restrict__ Df,
             const __bf16* __restrict__ Gb, const float* __restrict__ bias,
             __bf16* __restrict__ Eb, float* __restrict__ norm2) {
  constexpr int K = F;  // 768
  __shared__ __bf16 As[128 * 64];
  __shared__ __bf16 Bs[128 * 64];
  __shared__ float ssum[128];
  const int tid  = threadIdx.x;
  const int wave = tid >> 6;
  const int lane = tid & 63;
  const int by = blockIdx.y;
  const bool isX = (by < B / 128);
  const float* A = isX ? Xf : Df;
  const int m0 = isX ? by * 128 : (by - B / 128) * 128;
  const int Mr = isX ? B : N;
  const int g0 = by * 128;              // row offset into Eb / norm2
  const int n0 = blockIdx.x * 128;      // e-dim tile
  if (tid < 128) ssum[tid] = 0.0f;

  // staging: thread t -> row=(t>>3)+q*32, global colgrp (t&7)^(row&7).
  // LDS dest element q*2048 + tid*8 == row*64 + (t&7)*8 (same layout as the
  // old gload_lds path, so the fragment reads below are unchanged).
  const int srow = tid >> 3;
  const int scg  = (tid & 7) ^ (srow & 7);
  const float*  ga[4];
  const __bf16* gb[4];
  __bf16* la[4];
  __bf16* lb[4];
#pragma unroll
  for (int q = 0; q < 4; ++q) {
    const int row = srow + q * 32;
    int arow = m0 + row; if (arow >= Mr) arow = Mr - 1;
    const int brow = n0 + row;                       // < 512 always
    ga[q] = A  + (size_t)arow * K + scg * 8;
    gb[q] = Gb + (size_t)brow * K + scg * 8;
    la[q] = &As[q * 2048 + tid * 8];
    lb[q] = &Bs[q * 2048 + tid * 8];
  }

  const int mw = (wave & 1) * 64;
  const int nw = (wave >> 1) * 64;
  const int quad = lane >> 4;
  const int l15  = lane & 15;
  f32x4 acc[4][4] = {};

  for (int kb = 0; kb < K; kb += 64) {
    // B: async direct-to-LDS (bf16)
#pragma unroll
    for (int q = 0; q < 4; ++q) gload_lds16(gb[q] + kb, lb[q]);
    // A: reg-stage fp32 -> bf16 (issue all loads first for overlap)
    float4 av[4][2];
#pragma unroll
    for (int q = 0; q < 4; ++q) {
      av[q][0] = *(const float4*)(ga[q] + kb);
      av[q][1] = *(const float4*)(ga[q] + kb + 4);
    }
#pragma unroll
    for (int q = 0; q < 4; ++q) {
      bf16x8 o;
      o[0] = (__bf16)av[q][0].x; o[1] = (__bf16)av[q][0].y;
      o[2] = (__bf16)av[q][0].z; o[3] = (__bf16)av[q][0].w;
      o[4] = (__bf16)av[q][1].x; o[5] = (__bf16)av[q][1].y;
      o[6] = (__bf16)av[q][1].z; o[7] = (__bf16)av[q][1].w;
      *(bf16x8*)la[q] = o;
    }
    __syncthreads();
#pragma unroll
    for (int h = 0; h < 2; ++h) {
      bf16x8 af[4], bfr[4];
#pragma unroll
      for (int i = 0; i < 4; ++i) {
        const int rr = mw + i * 16 + l15;
        af[i] = *(const bf16x8*)&As[rr * 64 + ((quad + h * 4) ^ (rr & 7)) * 8];
      }
#pragma unroll
      for (int j = 0; j < 4; ++j) {
        const int rr = nw + j * 16 + l15;
        bfr[j] = *(const bf16x8*)&Bs[rr * 64 + ((quad + h * 4) ^ (rr & 7)) * 8];
      }
#pragma unroll
      for (int i = 0; i < 4; ++i)
#pragma unroll
        for (int j = 0; j < 4; ++j)
          acc[i][j] = __builtin_amdgcn_mfma_f32_16x16x32_bf16(af[i], bfr[j], acc[i][j], 0, 0, 0);
    }
    __syncthreads();
  }

  // epilogue: bf16 store + row sum-of-squares.  C/D: col=l15, row=quad*4+reg
#pragma unroll
  for (int i = 0; i < 4; ++i) {
    float part[4] = {0.0f, 0.0f, 0.0f, 0.0f};
#pragma unroll
    for (int j = 0; j < 4; ++j) {
      const int col = n0 + nw + j * 16 + l15;
      const float bv = bias[col];
#pragma unroll
      for (int rr = 0; rr < 4; ++rr) {
        const int row = mw + i * 16 + quad * 4 + rr;   // tile-local
        if (m0 + row < Mr) {
          const __bf16 hv = (__bf16)(acc[i][j][rr] + bv);
          Eb[(size_t)(g0 + row) * E + col] = hv;
          const float vb = (float)hv;
          part[rr] += vb * vb;
        }
      }
    }
#pragma unroll
    for (int rr = 0; rr < 4; ++rr) {
      float v = part[rr];
      v += __shfl_xor(v, 1);
      v += __shfl_xor(v, 2);
      v += __shfl_xor(v, 4);
      v += __shfl_xor(v, 8);
      if (l15 == 0) atomicAdd(&ssum[mw + i * 16 + quad * 4 + rr], v);
    }
  }
  __syncthreads();
  if (tid < 128 && m0 + tid < Mr) atomicAdd(&norm2[g0 + tid], ssum[tid]);
}

// ------------------------- fused Minerva GEMM ------------------------------
// acc = Xe@De^T (unnormalized, K=512); epilogue uses
//   s^3*rh = acc^3 * ix^3 * (id^3*rh),  ix^3 hoisted out of the j-loop.
// m-fast panel ordering: consecutive blocks share the n-progression so each
// XCD's L2 holds a small Xn slice + the Dn panel.
// launch_bounds(256,4): 4 blocks/CU (16 waves) - LDS 133KB/160KB, unified
// VGPR 64 arch + 64 AGPR = 128/wave (the 16-waves/CU occupancy step).

__global__ __launch_bounds__(256, 4)
void k_minerva(const __bf16* __restrict__ Xe, const __bf16* __restrict__ De,
               const float* __restrict__ norm2, const float* __restrict__ rh,
               float* __restrict__ logits) {
  constexpr int K  = 512;
  constexpr int MT = B / 128;          // 32
  constexpr int NT = (N + 127) / 128;  // 157
  constexpr int W  = 20;               // panel width (n-tiles)
  __shared__ __bf16 As[128 * 64];
  __shared__ __bf16 Bs[128 * 64];
  __shared__ float lsum[128];
  const int tid  = threadIdx.x;
  const int lane = tid & 63;
  const int wave = tid >> 6;

  // panel decomposition, m-fast within panel
  const int bid   = blockIdx.x;
  const int panel = bid / (W * MT);
  const int bn    = panel * W;
  const int rem   = bid - panel * (W * MT);
  const int mt    = rem % MT;
  const int nt    = bn + rem / MT;
  const int m0 = mt * 128, n0 = nt * 128;
  if (tid < 128) lsum[tid] = 0.0f;

  const int srow = tid >> 3;
  const int scg  = (tid & 7) ^ (srow & 7);
  const __bf16* ga[4];
  const __bf16* gb[4];
  __bf16* la[4];
  __bf16* lb[4];
#pragma unroll
  for (int q = 0; q < 4; ++q) {
    const int row = srow + q * 32;
    const int arow = m0 + row;                       // < 4096 always
    int brow = n0 + row; if (brow >= N) brow = N - 1;
    ga[q] = Xe + (size_t)arow * K + scg * 8;
    gb[q] = De + (size_t)brow * K + scg * 8;
    la[q] = &As[q * 2048 + tid * 8];
    lb[q] = &Bs[q * 2048 + tid * 8];
  }

  const int mw = (wave & 1) * 64;
  const int nw = (wave >> 1) * 64;
  const int quad = lane >> 4;
  const int l15  = lane & 15;
  f32x4 acc[4][4] = {};

  for (int kb = 0; kb < K; kb += 64) {
#pragma unroll
    for (int q = 0; q < 4; ++q) gload_lds16(ga[q] + kb, la[q]);
#pragma unroll
    for (int q = 0; q < 4; ++q) gload_lds16(gb[q] + kb, lb[q]);
    __syncthreads();
#pragma unroll
    for (int h = 0; h < 2; ++h) {
      bf16x8 af[4], bfr[4];
#pragma unroll
      for (int i = 0; i < 4; ++i) {
        const int rr = mw + i * 16 + l15;
        af[i] = *(const bf16x8*)&As[rr * 64 + ((quad + h * 4) ^ (rr & 7)) * 8];
      }
#pragma unroll
      for (int j = 0; j < 4; ++j) {
        const int rr = nw + j * 16 + l15;
        bfr[j] = *(const bf16x8*)&Bs[rr * 64 + ((quad + h * 4) ^ (rr & 7)) * 8];
      }
#pragma unroll
      for (int i = 0; i < 4; ++i)
#pragma unroll
        for (int j = 0; j < 4; ++j)
          acc[i][j] = __builtin_amdgcn_mfma_f32_16x16x32_bf16(af[i], bfr[j], acc[i][j], 0, 0, 0);
    }
    __syncthreads();
  }

  // ---- epilogue ----
  float id3rh[4];
#pragma unroll
  for (int j = 0; j < 4; ++j) {
    const int col = n0 + nw + j * 16 + l15;
    if (col < N) {
      const float id = 1.0f / fmaxf(sqrtf(norm2[B + col]), 1e-12f);
      id3rh[j] = id * id * id * rh[col];
    } else id3rh[j] = 0.0f;   // kills padded/clamped cols
  }
#pragma unroll
  for (int i = 0; i < 4; ++i) {
    float ix3[4];
#pragma unroll
    for (int rr = 0; rr < 4; ++rr) {
      const int row = m0 + mw + i * 16 + quad * 4 + rr;   // < 4096
      const float ix = 1.0f / fmaxf(sqrtf(norm2[row]), 1e-12f);
      ix3[rr] = ix * ix * ix;
    }
    float part[4] = {0.0f, 0.0f, 0.0f, 0.0f};
#pragma unroll
    for (int j = 0; j < 4; ++j)
#pragma unroll
      for (int rr = 0; rr < 4; ++rr) {
        const float a = acc[i][j][rr];
        const float a2 = a * a;
        part[rr] = fmaf(a2 * a, id3rh[j], part[rr]);
      }
#pragma unroll
    for (int rr = 0; rr < 4; ++rr) {
      float v = part[rr] * ix3[rr];
      v += __shfl_xor(v, 1);
      v += __shfl_xor(v, 2);
      v += __shfl_xor(v, 4);
      v += __shfl_xor(v, 8);
      if (l15 == 0) atomicAdd(&lsum[mw + i * 16 + quad * 4 + rr], v);
    }
  }
  __syncthreads();
  if (tid < 128) atomicAdd(&logits[m0 + tid], lsum[tid]);
}

// ------------------------- finalize ----------------------------------------

__global__ void k_finalize(const float* __restrict__ logits, float* __restrict__ out, int n) {
  int i = blockIdx.x * blockDim.x + threadIdx.x;
  if (i < n) {
    float L = logits[i];
    out[i] = L;
    out[n + i] = 1.0f / (1.0f + expf(-L));
  }
}

// ------------------------- launcher ----------------------------------------

extern "C" void kernel_launch(void* const* d_in, const int* in_sizes, int n_in,
                              void* d_out, int out_size, void* d_ws, size_t ws_size,
                              hipStream_t stream) {
  const float* X   = (const float*)d_in[0];
  const float* D   = (const float*)d_in[1];
  const float* r   = (const float*)d_in[2];
  const float* g_w = (const float*)d_in[3];
  const float* g_b = (const float*)d_in[4];
  const float* h_w = (const float*)d_in[5];
  const float* h_b = (const float*)d_in[6];
  float* out = (float*)d_out;

  // ws layout (bytes), 256-aligned, total ~25.7 MB
  char* ws = (char*)d_ws;
  __bf16* Gb    = (__bf16*)(ws + 0);             // 512*768*2    = 786,432
  __bf16* Eb    = (__bf16*)(ws + 786432);        // 24096*512*2  = 24,674,304
  float*  rh    = (float*) (ws + 25460736);      // 20000*4      = 80,000
  float*  norm2 = (float*) (ws + 25540736);      // 24096*4      = 96,384
  float*  lg    = (float*) (ws + 25637120);      // 4096*4       = 16,384

  // 1. slim prep: G convert + rh + zero (384*256 = 98304 threads covers all)
  k_prep<<<384, 256, 0, stream>>>(g_w, r, h_w, h_b, Gb, rh, lg, norm2);

  // 2. combined embedding GEMM (A reg-staged from fp32), bf16 out + norm2
  k_embed<<<dim3(E / 128, B / 128 + (N + 127) / 128), 256, 0, stream>>>(
      X, D, Gb, g_b, Eb, norm2);

  // 3. fused cosine^3-weighted retrieval (normalization folded into epilogue)
  k_minerva<<<157 * 32, 256, 0, stream>>>(Eb, Eb + (size_t)B * E, norm2, rh, lg);

  // 4. logits + sigmoid
  k_finalize<<<(B + 255) / 256, 256, 0, stream>>>(lg, out, B);
}

// Round 5
// 255.451 us; speedup vs baseline: 1.0554x; 1.0481x over previous
//
#include <hip/hip_runtime.h>
#include <cstdint>

// ---------------------------------------------------------------------------
// minerva_transform: logits = (l2(Xe) @ l2(De)^T)^3 @ rh ; preds = sigmoid
// R8 vs R7 (two low-risk changes, separately attributable):
//  1. k_minerva epilogue de-transcendentalized: new tiny k_weights pass
//     precomputes ix3[row]=(1/max(sqrt(n2),eps))^3 and wcol[col]=id^3*rh.
//     Epilogue had ~20 dependent sqrt/rcp chains (~400cyc/wave, ~30% of block
//     time with MFMA idle - the MfmaUtil29/VALUBusy40 signature). Bit-identical
//     math (same exprs), zero register delta.
//  2. k_embed A-side register prefetch (same av regs, zero VGPR delta):
//     next K-step's fp32 loads issued right after cvt/ds_write, so their
//     latency is absorbed by the pre-MFMA barrier drain.
// ---------------------------------------------------------------------------

typedef __attribute__((ext_vector_type(4))) float  f32x4;
typedef __attribute__((ext_vector_type(8))) __bf16 bf16x8;
typedef __attribute__((ext_vector_type(4))) __bf16 bf16x4;

constexpr int B = 4096, N = 20000, F = 768, E = 512;

#define AS1CAST(p) ((__attribute__((address_space(1))) unsigned int*)(uintptr_t)(p))
#define AS3CAST(p) ((__attribute__((address_space(3))) unsigned int*)(uintptr_t)(p))

__device__ __forceinline__ void gload_lds16(const void* g, void* l) {
  // 16B/lane, LDS dest = wave-uniform base + lane*16 (layout guarantees this)
  __builtin_amdgcn_global_load_lds(AS1CAST(g), AS3CAST(l), 16, 0, 0);
}

// ------------------------- slim prep ---------------------------------------
// G fp32->bf16 (tiny), rh = (2r-1)*hw+hb, zero lg/norm2.  Grid covers all.

__global__ void k_prep(const float* __restrict__ G, const float* __restrict__ r,
                       const float* __restrict__ hw, const float* __restrict__ hb,
                       __bf16* __restrict__ Gb, float* __restrict__ rh,
                       float* __restrict__ lg, float* __restrict__ norm2) {
  const int t = blockIdx.x * blockDim.x + threadIdx.x;
  constexpr int nG = E * F / 4;   // 98304 float4 groups
  if (t < nG) {
    float4 v = ((const float4*)G)[t];
    bf16x4 o;
    o[0] = (__bf16)v.x; o[1] = (__bf16)v.y; o[2] = (__bf16)v.z; o[3] = (__bf16)v.w;
    ((bf16x4*)Gb)[t] = o;
  }
  if (t < N) rh[t] = (2.0f * r[t] - 1.0f) * hw[0] + hb[0];
  if (t < B) lg[t] = 0.0f;
  if (t < B + N) norm2[t] = 0.0f;
}

// ------------------------- combined embedding GEMM -------------------------
// row-tiles 0..31 = X, 32..188 = D.  Eb[g,e] = bf16(sum_k A[m,k]G[e,k]+b[e]),
// norm2[g] += sum_e Eb[g,e]^2.  BK=64, XOR-swizzled LDS (conflict-free).
// A-side: reg-staged fp32->bf16 with one-step register prefetch;
// B-side (G): async global_load_lds from pre-converted Gb.

__global__ __launch_bounds__(256, 3)
void k_embed(const float* __restrict__ Xf, const float* __restrict__ Df,
             const __bf16* __restrict__ Gb, const float* __restrict__ bias,
             __bf16* __restrict__ Eb, float* __restrict__ norm2) {
  constexpr int K = F;  // 768
  __shared__ __bf16 As[128 * 64];
  __shared__ __bf16 Bs[128 * 64];
  __shared__ float ssum[128];
  const int tid  = threadIdx.x;
  const int wave = tid >> 6;
  const int lane = tid & 63;
  const int by = blockIdx.y;
  const bool isX = (by < B / 128);
  const float* A = isX ? Xf : Df;
  const int m0 = isX ? by * 128 : (by - B / 128) * 128;
  const int Mr = isX ? B : N;
  const int g0 = by * 128;              // row offset into Eb / norm2
  const int n0 = blockIdx.x * 128;      // e-dim tile
  if (tid < 128) ssum[tid] = 0.0f;

  // staging: thread t -> row=(t>>3)+q*32, global colgrp (t&7)^(row&7).
  // LDS dest element q*2048 + tid*8 == row*64 + (t&7)*8.
  const int srow = tid >> 3;
  const int scg  = (tid & 7) ^ (srow & 7);
  const float*  ga[4];
  const __bf16* gb[4];
  __bf16* la[4];
  __bf16* lb[4];
#pragma unroll
  for (int q = 0; q < 4; ++q) {
    const int row = srow + q * 32;
    int arow = m0 + row; if (arow >= Mr) arow = Mr - 1;
    const int brow = n0 + row;                       // < 512 always
    ga[q] = A  + (size_t)arow * K + scg * 8;
    gb[q] = Gb + (size_t)brow * K + scg * 8;
    la[q] = &As[q * 2048 + tid * 8];
    lb[q] = &Bs[q * 2048 + tid * 8];
  }

  const int mw = (wave & 1) * 64;
  const int nw = (wave >> 1) * 64;
  const int quad = lane >> 4;
  const int l15  = lane & 15;
  f32x4 acc[4][4] = {};

  // preload A step 0 into registers
  float4 av[4][2];
#pragma unroll
  for (int q = 0; q < 4; ++q) {
    av[q][0] = *(const float4*)(ga[q]);
    av[q][1] = *(const float4*)(ga[q] + 4);
  }

#pragma unroll 1
  for (int kb = 0; kb < K; kb += 64) {
    // B: async direct-to-LDS (bf16)
#pragma unroll
    for (int q = 0; q < 4; ++q) gload_lds16(gb[q] + kb, lb[q]);
    // A: cvt current step (av ready - loads issued one step ago)
#pragma unroll
    for (int q = 0; q < 4; ++q) {
      bf16x8 o;
      o[0] = (__bf16)av[q][0].x; o[1] = (__bf16)av[q][0].y;
      o[2] = (__bf16)av[q][0].z; o[3] = (__bf16)av[q][0].w;
      o[4] = (__bf16)av[q][1].x; o[5] = (__bf16)av[q][1].y;
      o[6] = (__bf16)av[q][1].z; o[7] = (__bf16)av[q][1].w;
      *(bf16x8*)la[q] = o;
    }
    // A: prefetch next step into the same (now dead) registers
    if (kb + 64 < K) {
#pragma unroll
      for (int q = 0; q < 4; ++q) {
        av[q][0] = *(const float4*)(ga[q] + kb + 64);
        av[q][1] = *(const float4*)(ga[q] + kb + 68);
      }
    }
    __syncthreads();
#pragma unroll
    for (int h = 0; h < 2; ++h) {
      bf16x8 af[4], bfr[4];
#pragma unroll
      for (int i = 0; i < 4; ++i) {
        const int rr = mw + i * 16 + l15;
        af[i] = *(const bf16x8*)&As[rr * 64 + ((quad + h * 4) ^ (rr & 7)) * 8];
      }
#pragma unroll
      for (int j = 0; j < 4; ++j) {
        const int rr = nw + j * 16 + l15;
        bfr[j] = *(const bf16x8*)&Bs[rr * 64 + ((quad + h * 4) ^ (rr & 7)) * 8];
      }
#pragma unroll
      for (int i = 0; i < 4; ++i)
#pragma unroll
        for (int j = 0; j < 4; ++j)
          acc[i][j] = __builtin_amdgcn_mfma_f32_16x16x32_bf16(af[i], bfr[j], acc[i][j], 0, 0, 0);
    }
    __syncthreads();
  }

  // epilogue: bf16 store + row sum-of-squares.  C/D: col=l15, row=quad*4+reg
#pragma unroll
  for (int i = 0; i < 4; ++i) {
    float part[4] = {0.0f, 0.0f, 0.0f, 0.0f};
#pragma unroll
    for (int j = 0; j < 4; ++j) {
      const int col = n0 + nw + j * 16 + l15;
      const float bv = bias[col];
#pragma unroll
      for (int rr = 0; rr < 4; ++rr) {
        const int row = mw + i * 16 + quad * 4 + rr;   // tile-local
        if (m0 + row < Mr) {
          const __bf16 hv = (__bf16)(acc[i][j][rr] + bv);
          Eb[(size_t)(g0 + row) * E + col] = hv;
          const float vb = (float)hv;
          part[rr] += vb * vb;
        }
      }
    }
#pragma unroll
    for (int rr = 0; rr < 4; ++rr) {
      float v = part[rr];
      v += __shfl_xor(v, 1);
      v += __shfl_xor(v, 2);
      v += __shfl_xor(v, 4);
      v += __shfl_xor(v, 8);
      if (l15 == 0) atomicAdd(&ssum[mw + i * 16 + quad * 4 + rr], v);
    }
  }
  __syncthreads();
  if (tid < 128 && m0 + tid < Mr) atomicAdd(&norm2[g0 + tid], ssum[tid]);
}

// ------------------------- weight precompute -------------------------------
// ix3[row] = (1/max(sqrt(norm2),eps))^3 ; wcol[col] = id^3 * rh[col].
// Same expressions/order as the old in-epilogue math -> bit-identical.

__global__ void k_weights(const float* __restrict__ norm2, const float* __restrict__ rh,
                          float* __restrict__ ix3, float* __restrict__ wcol) {
  const int t = blockIdx.x * blockDim.x + threadIdx.x;
  if (t < B) {
    const float ix = 1.0f / fmaxf(sqrtf(norm2[t]), 1e-12f);
    ix3[t] = ix * ix * ix;
  }
  if (t < N) {
    const float id = 1.0f / fmaxf(sqrtf(norm2[B + t]), 1e-12f);
    wcol[t] = id * id * id * rh[t];
  }
}

// ------------------------- fused Minerva GEMM ------------------------------
// acc = Xe@De^T (unnormalized, K=512); epilogue:
//   s^3*rh = acc^3 * ix3[row] * wcol[col]   (all norm math precomputed).
// m-fast panel ordering for per-XCD L2 fit.  64 arch VGPR + 64 AGPR =
// 128/wave -> 16 waves/CU (the occupancy step); keep it that way.

__global__ __launch_bounds__(256, 4)
void k_minerva(const __bf16* __restrict__ Xe, const __bf16* __restrict__ De,
               const float* __restrict__ ix3a, const float* __restrict__ wcol,
               float* __restrict__ logits) {
  constexpr int K  = 512;
  constexpr int MT = B / 128;          // 32
  constexpr int NT = (N + 127) / 128;  // 157
  constexpr int W  = 20;               // panel width (n-tiles)
  __shared__ __bf16 As[128 * 64];
  __shared__ __bf16 Bs[128 * 64];
  __shared__ float lsum[128];
  const int tid  = threadIdx.x;
  const int lane = tid & 63;
  const int wave = tid >> 6;

  // panel decomposition, m-fast within panel
  const int bid   = blockIdx.x;
  const int panel = bid / (W * MT);
  const int bn    = panel * W;
  const int rem   = bid - panel * (W * MT);
  const int mt    = rem % MT;
  const int nt    = bn + rem / MT;
  const int m0 = mt * 128, n0 = nt * 128;
  if (tid < 128) lsum[tid] = 0.0f;

  const int srow = tid >> 3;
  const int scg  = (tid & 7) ^ (srow & 7);
  const __bf16* ga[4];
  const __bf16* gb[4];
  __bf16* la[4];
  __bf16* lb[4];
#pragma unroll
  for (int q = 0; q < 4; ++q) {
    const int row = srow + q * 32;
    const int arow = m0 + row;                       // < 4096 always
    int brow = n0 + row; if (brow >= N) brow = N - 1;
    ga[q] = Xe + (size_t)arow * K + scg * 8;
    gb[q] = De + (size_t)brow * K + scg * 8;
    la[q] = &As[q * 2048 + tid * 8];
    lb[q] = &Bs[q * 2048 + tid * 8];
  }

  const int mw = (wave & 1) * 64;
  const int nw = (wave >> 1) * 64;
  const int quad = lane >> 4;
  const int l15  = lane & 15;
  f32x4 acc[4][4] = {};

  for (int kb = 0; kb < K; kb += 64) {
#pragma unroll
    for (int q = 0; q < 4; ++q) gload_lds16(ga[q] + kb, la[q]);
#pragma unroll
    for (int q = 0; q < 4; ++q) gload_lds16(gb[q] + kb, lb[q]);
    __syncthreads();
#pragma unroll
    for (int h = 0; h < 2; ++h) {
      bf16x8 af[4], bfr[4];
#pragma unroll
      for (int i = 0; i < 4; ++i) {
        const int rr = mw + i * 16 + l15;
        af[i] = *(const bf16x8*)&As[rr * 64 + ((quad + h * 4) ^ (rr & 7)) * 8];
      }
#pragma unroll
      for (int j = 0; j < 4; ++j) {
        const int rr = nw + j * 16 + l15;
        bfr[j] = *(const bf16x8*)&Bs[rr * 64 + ((quad + h * 4) ^ (rr & 7)) * 8];
      }
#pragma unroll
      for (int i = 0; i < 4; ++i)
#pragma unroll
        for (int j = 0; j < 4; ++j)
          acc[i][j] = __builtin_amdgcn_mfma_f32_16x16x32_bf16(af[i], bfr[j], acc[i][j], 0, 0, 0);
    }
    __syncthreads();
  }

  // ---- epilogue (no transcendentals: all weights precomputed) ----
  float w4[4];
#pragma unroll
  for (int j = 0; j < 4; ++j) {
    const int col = n0 + nw + j * 16 + l15;
    w4[j] = (col < N) ? wcol[col] : 0.0f;   // kills padded/clamped cols
  }
#pragma unroll
  for (int i = 0; i < 4; ++i) {
    float x3[4];
#pragma unroll
    for (int rr = 0; rr < 4; ++rr)
      x3[rr] = ix3a[m0 + mw + i * 16 + quad * 4 + rr];   // broadcast loads
    float part[4] = {0.0f, 0.0f, 0.0f, 0.0f};
#pragma unroll
    for (int j = 0; j < 4; ++j)
#pragma unroll
      for (int rr = 0; rr < 4; ++rr) {
        const float a = acc[i][j][rr];
        const float a2 = a * a;
        part[rr] = fmaf(a2 * a, w4[j], part[rr]);
      }
#pragma unroll
    for (int rr = 0; rr < 4; ++rr) {
      float v = part[rr] * x3[rr];
      v += __shfl_xor(v, 1);
      v += __shfl_xor(v, 2);
      v += __shfl_xor(v, 4);
      v += __shfl_xor(v, 8);
      if (l15 == 0) atomicAdd(&lsum[mw + i * 16 + quad * 4 + rr], v);
    }
  }
  __syncthreads();
  if (tid < 128) atomicAdd(&logits[m0 + tid], lsum[tid]);
}

// ------------------------- finalize ----------------------------------------

__global__ void k_finalize(const float* __restrict__ logits, float* __restrict__ out, int n) {
  int i = blockIdx.x * blockDim.x + threadIdx.x;
  if (i < n) {
    float L = logits[i];
    out[i] = L;
    out[n + i] = 1.0f / (1.0f + expf(-L));
  }
}

// ------------------------- launcher ----------------------------------------

extern "C" void kernel_launch(void* const* d_in, const int* in_sizes, int n_in,
                              void* d_out, int out_size, void* d_ws, size_t ws_size,
                              hipStream_t stream) {
  const float* X   = (const float*)d_in[0];
  const float* D   = (const float*)d_in[1];
  const float* r   = (const float*)d_in[2];
  const float* g_w = (const float*)d_in[3];
  const float* g_b = (const float*)d_in[4];
  const float* h_w = (const float*)d_in[5];
  const float* h_b = (const float*)d_in[6];
  float* out = (float*)d_out;

  // ws layout (bytes), 256-aligned, total ~25.8 MB
  char* ws = (char*)d_ws;
  __bf16* Gb    = (__bf16*)(ws + 0);             // 512*768*2    = 786,432
  __bf16* Eb    = (__bf16*)(ws + 786432);        // 24096*512*2  = 24,674,304
  float*  rh    = (float*) (ws + 25460736);      // 20000*4      = 80,000
  float*  norm2 = (float*) (ws + 25540736);      // 24096*4      = 96,384
  float*  lg    = (float*) (ws + 25637120);      // 4096*4       = 16,384
  float*  ix3   = (float*) (ws + 25653504);      // 4096*4       = 16,384
  float*  wcol  = (float*) (ws + 25669888);      // 20000*4      = 80,000

  // 1. slim prep: G convert + rh + zero (384*256 = 98304 threads covers all)
  k_prep<<<384, 256, 0, stream>>>(g_w, r, h_w, h_b, Gb, rh, lg, norm2);

  // 2. combined embedding GEMM (A reg-staged from fp32 w/ prefetch)
  k_embed<<<dim3(E / 128, B / 128 + (N + 127) / 128), 256, 0, stream>>>(
      X, D, Gb, g_b, Eb, norm2);

  // 3. normalization weights (tiny)
  k_weights<<<(N + 255) / 256, 256, 0, stream>>>(norm2, rh, ix3, wcol);

  // 4. fused cosine^3-weighted retrieval (precomputed weights in epilogue)
  k_minerva<<<157 * 32, 256, 0, stream>>>(Eb, Eb + (size_t)B * E, ix3, wcol, lg);

  // 5. logits + sigmoid
  k_finalize<<<(B + 255) / 256, 256, 0, stream>>>(lg, out, B);
}